// Round 4
// baseline (132.945 us; speedup 1.0000x reference)
//
#include <hip/hip_runtime.h>

#define NQ 22
#define DIM (1 << NQ)
#define TILE 2048
#define LOG_TILE 11

typedef float fx4 __attribute__((ext_vector_type(4)));

// Precompute B[l] = sum over pairs p>q (LSB positions 0..10) both set in l of
// U[(21-p)*22 + (21-q)].  2048 entries, written to workspace.
__global__ __launch_bounds__(256) void ryd_precompute_B(const float* __restrict__ U,
                                                        float* __restrict__ Btab) {
    int t = blockIdx.x * blockDim.x + threadIdx.x;  // 0..2047
    __shared__ float Us[NQ * NQ];
    for (int i = threadIdx.x; i < NQ * NQ; i += blockDim.x) Us[i] = U[i];
    __syncthreads();
    float b = 0.f;
    #pragma unroll
    for (int p = 1; p <= 10; ++p) {
        if ((t >> p) & 1) {
            #pragma unroll
            for (int q = 0; q < p; ++q) {
                if ((t >> q) & 1) b += Us[(21 - p) * NQ + (21 - q)];
            }
        }
    }
    Btab[t] = b;
}

__device__ __forceinline__ float4 ntload4(const float* p) {
    fx4 v = __builtin_nontemporal_load((const fx4*)p);
    return make_float4(v.x, v.y, v.z, v.w);
}

#define ACC8(a0, a1, b0, b1)                                                \
    do {                                                                    \
        ar[0] += (a0).x; ar[1] += (a0).y; ar[2] += (a0).z; ar[3] += (a0).w; \
        ar[4] += (a1).x; ar[5] += (a1).y; ar[6] += (a1).z; ar[7] += (a1).w; \
        ai[0] += (b0).x; ai[1] += (b0).y; ai[2] += (b0).z; ai[3] += (b0).w; \
        ai[4] += (b1).x; ai[5] += (b1).y; ai[6] += (b1).z; ai[7] += (b1).w; \
    } while (0)

// R0 structure (verified correct): 2048 blocks x 256 threads, one 2048-elem
// tile per block, 8 elems/thread. Changes vs R0: register budget 128
// (__launch_bounds__(256,4)) so more loads stay in flight; the 3 cross-XCD
// flips (global bits 11..13 = H bits 0..2, since XCD = blockIdx%8) are
// hoisted to nontemporal loads issued first and accumulated last.
__global__ __launch_bounds__(256, 4) void ryd_main(
    const float* __restrict__ sr_g, const float* __restrict__ si_g,
    const float* __restrict__ rabi, const float* __restrict__ detune,
    const float* __restrict__ U, const float* __restrict__ Btab,
    float* __restrict__ out) {
    __shared__ float sr[TILE];
    __shared__ float si[TILE];
    __shared__ float AD[12];  // [0..10] = Dq[q] cross sums, [11] = A(h)

    const int h = blockIdx.x;        // high 11 bits (global bits 11..21)
    const int tid = threadIdx.x;     // 0..255
    const int m0 = tid << 3;         // local element base (8/thread)
    const int base = h << LOG_TILE;  // global tile base

    // Own tile (real+imag): global -> regs -> LDS.
    float4 r0 = *(const float4*)(sr_g + base + m0);
    float4 r1 = *(const float4*)(sr_g + base + m0 + 4);
    float4 i0 = *(const float4*)(si_g + base + m0);
    float4 i1 = *(const float4*)(si_g + base + m0 + 4);
    *(float4*)(sr + m0) = r0;
    *(float4*)(sr + m0 + 4) = r1;
    *(float4*)(si + m0) = i0;
    *(float4*)(si + m0 + 4) = i1;

    // FAR flips (cross-XCD, highest latency): issue now, consume last.
    // h^1, h^2, h^4 = flips of global bits 11,12,13.
    const int fb0 = ((h ^ 1) << LOG_TILE) + m0;
    const int fb1 = ((h ^ 2) << LOG_TILE) + m0;
    const int fb2 = ((h ^ 4) << LOG_TILE) + m0;
    float4 f0r0 = ntload4(sr_g + fb0), f0r1 = ntload4(sr_g + fb0 + 4);
    float4 f0i0 = ntload4(si_g + fb0), f0i1 = ntload4(si_g + fb0 + 4);
    float4 f1r0 = ntload4(sr_g + fb1), f1r1 = ntload4(sr_g + fb1 + 4);
    float4 f1i0 = ntload4(si_g + fb1), f1i1 = ntload4(si_g + fb1 + 4);
    float4 f2r0 = ntload4(sr_g + fb2), f2r1 = ntload4(sr_g + fb2 + 4);
    float4 f2i0 = ntload4(si_g + fb2), f2i1 = ntload4(si_g + fb2 + 4);

    // B table for this thread's 8 low indices (L2-resident after 1st block).
    float4 B0 = *(const float4*)(Btab + m0);
    float4 B1 = *(const float4*)(Btab + m0 + 4);

    // Per-block diagonal prep (overlaps outstanding far loads).
    // tid 0..10: Dq[q] = sum_{hp set in h} U[(10-hp)*22 + (21-q)]
    // tid == 11: A(h)  = sum over pairs hp>hq set in h of U[(10-hp)*22 + (10-hq)]
    if (tid < 11) {
        int q = tid;
        float d = 0.f;
        #pragma unroll
        for (int hp = 0; hp <= 10; ++hp)
            if ((h >> hp) & 1) d += U[(10 - hp) * NQ + (21 - q)];
        AD[q] = d;
    } else if (tid == 11) {
        float a = 0.f;
        #pragma unroll
        for (int hp = 1; hp <= 10; ++hp) {
            if ((h >> hp) & 1) {
                #pragma unroll
                for (int hq = 0; hq < hp; ++hq)
                    if ((h >> hq) & 1) a += U[(10 - hp) * NQ + (10 - hq)];
            }
        }
        AD[11] = a;
    }

    float pr[8]  = {r0.x, r0.y, r0.z, r0.w, r1.x, r1.y, r1.z, r1.w};
    float pi_[8] = {i0.x, i0.y, i0.z, i0.w, i1.x, i1.y, i1.z, i1.w};

    // Flips of global bits 0..2: partners in this thread's own registers.
    float ar[8], ai[8];
    #pragma unroll
    for (int e = 0; e < 8; ++e) {
        ar[e] = pr[e ^ 1] + pr[e ^ 2] + pr[e ^ 4];
        ai[e] = pi_[e ^ 1] + pi_[e ^ 2] + pi_[e ^ 4];
    }

    __syncthreads();

    // NEAR global flips (same-XCD L2): global bits 14..21 = h ^ (8..1024).
    #pragma unroll
    for (int k = 3; k <= 10; ++k) {
        int pb = ((h ^ (1 << k)) << LOG_TILE) + m0;
        float4 a0 = *(const float4*)(sr_g + pb);
        float4 a1 = *(const float4*)(sr_g + pb + 4);
        float4 b0 = *(const float4*)(si_g + pb);
        float4 b1 = *(const float4*)(si_g + pb + 4);
        ACC8(a0, a1, b0, b1);
    }

    // LDS flips: tid masks 1..128 flip global bits 3..10.
    #pragma unroll
    for (int jj = 0; jj < 8; ++jj) {
        int pt = (tid ^ (1 << jj)) << 3;
        float4 a0 = *(const float4*)(sr + pt);
        float4 a1 = *(const float4*)(sr + pt + 4);
        float4 b0 = *(const float4*)(si + pt);
        float4 b1 = *(const float4*)(si + pt + 4);
        ACC8(a0, a1, b0, b1);
    }

    // Consume the far flips (loaded first, waited on last).
    ACC8(f0r0, f0r1, f0i0, f0i1);
    ACC8(f1r0, f1r1, f1i0, f1i1);
    ACC8(f2r0, f2r1, f2i0, f2i1);

    // Diagonal: diag(b) = A + B[l] + sum_{q set in l} (Dq[q]-det) - det*popc(h)
    const float det = detune[0];
    const float hrabi = 0.5f * rabi[0];
    float Dq0 = AD[0] - det;
    float Dq1 = AD[1] - det;
    float Dq2 = AD[2] - det;
    float diagBase = AD[11] - det * (float)__popc((unsigned)h);
    #pragma unroll
    for (int j = 0; j < 8; ++j)
        if ((tid >> j) & 1) diagBase += AD[j + 3] - det;

    float Bv[8] = {B0.x, B0.y, B0.z, B0.w, B1.x, B1.y, B1.z, B1.w};

    float orv[8], oiv[8];
    #pragma unroll
    for (int e = 0; e < 8; ++e) {
        float d = diagBase + Bv[e];
        if (e & 1) d += Dq0;
        if (e & 2) d += Dq1;
        if (e & 4) d += Dq2;
        orv[e] = hrabi * ar[e] + d * pr[e];
        oiv[e] = hrabi * ai[e] + d * pi_[e];
    }

    *(float4*)(out + base + m0)           = make_float4(orv[0], orv[1], orv[2], orv[3]);
    *(float4*)(out + base + m0 + 4)       = make_float4(orv[4], orv[5], orv[6], orv[7]);
    *(float4*)(out + DIM + base + m0)     = make_float4(oiv[0], oiv[1], oiv[2], oiv[3]);
    *(float4*)(out + DIM + base + m0 + 4) = make_float4(oiv[4], oiv[5], oiv[6], oiv[7]);
}

extern "C" void kernel_launch(void* const* d_in, const int* in_sizes, int n_in,
                              void* d_out, int out_size, void* d_ws, size_t ws_size,
                              hipStream_t stream) {
    const float* state_real = (const float*)d_in[0];
    const float* state_imag = (const float*)d_in[1];
    const float* rabi       = (const float*)d_in[2];
    const float* detune     = (const float*)d_in[3];
    const float* U          = (const float*)d_in[4];
    float* Btab = (float*)d_ws;  // 2048 floats = 8 KB
    float* out  = (float*)d_out;

    ryd_precompute_B<<<TILE / 256, 256, 0, stream>>>(U, Btab);
    ryd_main<<<DIM / TILE, 256, 0, stream>>>(state_real, state_imag, rabi, detune,
                                             U, Btab, out);
}

// Round 5
// 129.146 us; speedup vs baseline: 1.0294x; 1.0294x over previous
//
#include <hip/hip_runtime.h>

#define NQ 22
#define DIM (1 << NQ)
#define TILE 2048
#define LOG_TILE 11

typedef float fx4 __attribute__((ext_vector_type(4)));

// Precompute B[l] = sum over pairs p>q (LSB positions 0..10) both set in l of
// U[(21-p)*22 + (21-q)].  2048 entries, written to workspace.
__global__ __launch_bounds__(256) void ryd_precompute_B(const float* __restrict__ U,
                                                        float* __restrict__ Btab) {
    int t = blockIdx.x * blockDim.x + threadIdx.x;  // 0..2047
    __shared__ float Us[NQ * NQ];
    for (int i = threadIdx.x; i < NQ * NQ; i += blockDim.x) Us[i] = U[i];
    __syncthreads();
    float b = 0.f;
    #pragma unroll
    for (int p = 1; p <= 10; ++p) {
        if ((t >> p) & 1) {
            #pragma unroll
            for (int q = 0; q < p; ++q) {
                if ((t >> q) & 1) b += Us[(21 - p) * NQ + (21 - q)];
            }
        }
    }
    Btab[t] = b;
}

__device__ __forceinline__ float4 ntload4(const float* p) {
    fx4 v = __builtin_nontemporal_load((const fx4*)p);
    return make_float4(v.x, v.y, v.z, v.w);
}
__device__ __forceinline__ void ntstore4(float* p, float4 v) {
    fx4 t = {v.x, v.y, v.z, v.w};
    __builtin_nontemporal_store(t, (fx4*)p);
}

#define ACC8(a0, a1, b0, b1)                                                \
    do {                                                                    \
        ar[0] += (a0).x; ar[1] += (a0).y; ar[2] += (a0).z; ar[3] += (a0).w; \
        ar[4] += (a1).x; ar[5] += (a1).y; ar[6] += (a1).z; ar[7] += (a1).w; \
        ai[0] += (b0).x; ai[1] += (b0).y; ai[2] += (b0).z; ai[3] += (b0).w; \
        ai[4] += (b1).x; ai[5] += (b1).y; ai[6] += (b1).z; ai[7] += (b1).w; \
    } while (0)

// 2048 blocks x 256 threads, one 2048-elem tile per block, 8 elems/thread.
// __launch_bounds__(256,2): 256-VGPR budget so ALL 50 global float4 loads can
// be issued up front and stay in flight (full MLP); R3 showed that a 128-cap
// makes the compiler sink "prefetched" loads to their use point.
__global__ __launch_bounds__(256, 2) void ryd_main(
    const float* __restrict__ sr_g, const float* __restrict__ si_g,
    const float* __restrict__ rabi, const float* __restrict__ detune,
    const float* __restrict__ U, const float* __restrict__ Btab,
    float* __restrict__ out) {
    __shared__ float sr[TILE];
    __shared__ float si[TILE];
    __shared__ float AD[12];  // [0..10] = Dq[q] cross sums, [11] = A(h)

    const int h = blockIdx.x;        // high 11 bits (global bits 11..21)
    const int tid = threadIdx.x;     // 0..255
    const int m0 = tid << 3;         // local element base (8/thread)
    const int base = h << LOG_TILE;  // global tile base

    // ---- Issue ALL global loads up front, in consumption order. ----
    // (vmcnt drains in issue order: consume-early loads must be issued early.)
    // 1) own tile (consumed first: LDS staging + diag term)
    float4 r0 = *(const float4*)(sr_g + base + m0);
    float4 r1 = *(const float4*)(sr_g + base + m0 + 4);
    float4 i0 = *(const float4*)(si_g + base + m0);
    float4 i1 = *(const float4*)(si_g + base + m0 + 4);

    // 2) near flips (same-XCD L2): global bits 14..21 = h ^ (8..1024).
    float4 nr[8][2], ni[8][2];
    #pragma unroll
    for (int k = 3; k <= 10; ++k) {
        const int pb = ((h ^ (1 << k)) << LOG_TILE) + m0;
        nr[k - 3][0] = *(const float4*)(sr_g + pb);
        nr[k - 3][1] = *(const float4*)(sr_g + pb + 4);
        ni[k - 3][0] = *(const float4*)(si_g + pb);
        ni[k - 3][1] = *(const float4*)(si_g + pb + 4);
    }

    // 3) far flips (cross-XCD, nontemporal: don't pollute local L2).
    const int fb0 = ((h ^ 1) << LOG_TILE) + m0;
    const int fb1 = ((h ^ 2) << LOG_TILE) + m0;
    const int fb2 = ((h ^ 4) << LOG_TILE) + m0;
    float4 f0r0 = ntload4(sr_g + fb0), f0r1 = ntload4(sr_g + fb0 + 4);
    float4 f0i0 = ntload4(si_g + fb0), f0i1 = ntload4(si_g + fb0 + 4);
    float4 f1r0 = ntload4(sr_g + fb1), f1r1 = ntload4(sr_g + fb1 + 4);
    float4 f1i0 = ntload4(si_g + fb1), f1i1 = ntload4(si_g + fb1 + 4);
    float4 f2r0 = ntload4(sr_g + fb2), f2r1 = ntload4(sr_g + fb2 + 4);
    float4 f2i0 = ntload4(si_g + fb2), f2i1 = ntload4(si_g + fb2 + 4);

    // 4) B table (consumed in epilogue).
    float4 B0 = *(const float4*)(Btab + m0);
    float4 B1 = *(const float4*)(Btab + m0 + 4);

    // ---- Stage own tile to LDS (waits only on the 4 oldest loads). ----
    *(float4*)(sr + m0) = r0;
    *(float4*)(sr + m0 + 4) = r1;
    *(float4*)(si + m0) = i0;
    *(float4*)(si + m0 + 4) = i1;

    // Per-block diagonal prep (scalar-ish, overlaps outstanding vmem).
    if (tid < 11) {
        int q = tid;
        float d = 0.f;
        #pragma unroll
        for (int hp = 0; hp <= 10; ++hp)
            if ((h >> hp) & 1) d += U[(10 - hp) * NQ + (21 - q)];
        AD[q] = d;
    } else if (tid == 11) {
        float a = 0.f;
        #pragma unroll
        for (int hp = 1; hp <= 10; ++hp) {
            if ((h >> hp) & 1) {
                #pragma unroll
                for (int hq = 0; hq < hp; ++hq)
                    if ((h >> hq) & 1) a += U[(10 - hp) * NQ + (10 - hq)];
            }
        }
        AD[11] = a;
    }

    float pr[8]  = {r0.x, r0.y, r0.z, r0.w, r1.x, r1.y, r1.z, r1.w};
    float pi_[8] = {i0.x, i0.y, i0.z, i0.w, i1.x, i1.y, i1.z, i1.w};

    // Flips of global bits 0..2: partners in this thread's own registers.
    float ar[8], ai[8];
    #pragma unroll
    for (int e = 0; e < 8; ++e) {
        ar[e] = pr[e ^ 1] + pr[e ^ 2] + pr[e ^ 4];
        ai[e] = pi_[e ^ 1] + pi_[e ^ 2] + pi_[e ^ 4];
    }

    __syncthreads();

    // LDS flips (lgkm waits only; global loads still draining underneath):
    // tid masks 1..128 flip global bits 3..10.
    #pragma unroll
    for (int jj = 0; jj < 8; ++jj) {
        int pt = (tid ^ (1 << jj)) << 3;
        float4 a0 = *(const float4*)(sr + pt);
        float4 a1 = *(const float4*)(sr + pt + 4);
        float4 b0 = *(const float4*)(si + pt);
        float4 b1 = *(const float4*)(si + pt + 4);
        ACC8(a0, a1, b0, b1);
    }

    // Accumulate near flips, oldest-issued first.
    #pragma unroll
    for (int k = 0; k < 8; ++k) {
        ACC8(nr[k][0], nr[k][1], ni[k][0], ni[k][1]);
    }

    // Far flips last (longest latency, longest flight time).
    ACC8(f0r0, f0r1, f0i0, f0i1);
    ACC8(f1r0, f1r1, f1i0, f1i1);
    ACC8(f2r0, f2r1, f2i0, f2i1);

    // Diagonal: diag(b) = A + B[l] + sum_{q set in l} (Dq[q]-det) - det*popc(h)
    const float det = detune[0];
    const float hrabi = 0.5f * rabi[0];
    float Dq0 = AD[0] - det;
    float Dq1 = AD[1] - det;
    float Dq2 = AD[2] - det;
    float diagBase = AD[11] - det * (float)__popc((unsigned)h);
    #pragma unroll
    for (int j = 0; j < 8; ++j)
        if ((tid >> j) & 1) diagBase += AD[j + 3] - det;

    float Bv[8] = {B0.x, B0.y, B0.z, B0.w, B1.x, B1.y, B1.z, B1.w};

    float orv[8], oiv[8];
    #pragma unroll
    for (int e = 0; e < 8; ++e) {
        float d = diagBase + Bv[e];
        if (e & 1) d += Dq0;
        if (e & 2) d += Dq1;
        if (e & 4) d += Dq2;
        orv[e] = hrabi * ar[e] + d * pr[e];
        oiv[e] = hrabi * ai[e] + d * pi_[e];
    }

    // NT stores: out is write-once — keep it out of L2 so psi stays resident.
    ntstore4(out + base + m0,           make_float4(orv[0], orv[1], orv[2], orv[3]));
    ntstore4(out + base + m0 + 4,       make_float4(orv[4], orv[5], orv[6], orv[7]));
    ntstore4(out + DIM + base + m0,     make_float4(oiv[0], oiv[1], oiv[2], oiv[3]));
    ntstore4(out + DIM + base + m0 + 4, make_float4(oiv[4], oiv[5], oiv[6], oiv[7]));
}

extern "C" void kernel_launch(void* const* d_in, const int* in_sizes, int n_in,
                              void* d_out, int out_size, void* d_ws, size_t ws_size,
                              hipStream_t stream) {
    const float* state_real = (const float*)d_in[0];
    const float* state_imag = (const float*)d_in[1];
    const float* rabi       = (const float*)d_in[2];
    const float* detune     = (const float*)d_in[3];
    const float* U          = (const float*)d_in[4];
    float* Btab = (float*)d_ws;  // 2048 floats = 8 KB
    float* out  = (float*)d_out;

    ryd_precompute_B<<<TILE / 256, 256, 0, stream>>>(U, Btab);
    ryd_main<<<DIM / TILE, 256, 0, stream>>>(state_real, state_imag, rabi, detune,
                                             U, Btab, out);
}